// Round 5
// baseline (131.111 us; speedup 1.0000x reference)
//
#include <hip/hip_runtime.h>
#include <math.h>

#define HH 2048
#define WW 2048
#define HWP (HH*WW)          // plane stride (elements)
#define NBLK 32              // spatial 8x8 blocks per workgroup (256-col quarter strip)
#define SLOTH 72             // halves per (c,blk) slot; 144B stride -> conflict-free b128

typedef float     f2 __attribute__((ext_vector_type(2)));   // -> v_pk_*_f32
typedef _Float16  h8 __attribute__((ext_vector_type(8)));   // 16B LDS vector

// ---- f64 truth for 0.5*cos(pi*m/16); f32 casts == np.float32(A) exactly ----
#define C1d 0.49039264020161522
#define C2d 0.46193976625564337
#define C3d 0.41573480615127262
#define C4d 0.35355339059327379
#define C5d 0.27778511650980111
#define C6d 0.19134171618254489
#define C7d 0.097545161008064134
#define F(x) ((float)(x))

static constexpr float AFc[8][8] = {
 { F(C4d), F(C4d), F(C4d), F(C4d), F(C4d), F(C4d), F(C4d), F(C4d)},
 { F(C1d), F(C3d), F(C5d), F(C7d),-F(C7d),-F(C5d),-F(C3d),-F(C1d)},
 { F(C2d), F(C6d),-F(C6d),-F(C2d),-F(C2d),-F(C6d), F(C6d), F(C2d)},
 { F(C3d),-F(C7d),-F(C1d),-F(C5d), F(C5d), F(C1d), F(C7d),-F(C3d)},
 { F(C4d),-F(C4d),-F(C4d), F(C4d), F(C4d),-F(C4d),-F(C4d), F(C4d)},
 { F(C5d),-F(C1d), F(C7d), F(C3d),-F(C3d),-F(C7d), F(C1d),-F(C5d)},
 { F(C6d),-F(C2d), F(C2d),-F(C6d),-F(C6d), F(C2d),-F(C2d), F(C6d)},
 { F(C7d),-F(C5d), F(C3d),-F(C1d), F(C1d),-F(C3d), F(C5d),-F(C7d)}
};

__device__ __constant__ float g_AF[64] = {
  F(C4d), F(C4d), F(C4d), F(C4d), F(C4d), F(C4d), F(C4d), F(C4d),
  F(C1d), F(C3d), F(C5d), F(C7d),-F(C7d),-F(C5d),-F(C3d),-F(C1d),
  F(C2d), F(C6d),-F(C6d),-F(C2d),-F(C2d),-F(C6d), F(C6d), F(C2d),
  F(C3d),-F(C7d),-F(C1d),-F(C5d), F(C5d), F(C1d), F(C7d),-F(C3d),
  F(C4d),-F(C4d),-F(C4d), F(C4d), F(C4d),-F(C4d),-F(C4d), F(C4d),
  F(C5d),-F(C1d), F(C7d), F(C3d),-F(C3d),-F(C7d), F(C1d),-F(C5d),
  F(C6d),-F(C2d), F(C2d),-F(C6d),-F(C6d), F(C2d),-F(C2d), F(C6d),
  F(C7d),-F(C5d), F(C3d),-F(C1d), F(C1d),-F(C3d), F(C5d),-F(C7d)
};

__device__ __constant__ float g_Q[128] = {
 16,11,10,16,24,40,51,61,  12,12,14,19,26,58,60,55,
 14,13,16,24,40,57,69,56,  14,17,22,29,51,87,80,62,
 18,22,37,56,68,109,103,77, 24,35,55,64,81,104,113,92,
 49,64,78,87,103,121,120,101, 72,92,95,98,112,100,103,99,
 17,18,24,47,99,99,99,99,  18,21,26,66,99,99,99,99,
 24,26,56,99,99,99,99,99,  47,66,99,99,99,99,99,99,
 99,99,99,99,99,99,99,99,  99,99,99,99,99,99,99,99,
 99,99,99,99,99,99,99,99,  99,99,99,99,99,99,99,99};

// ---- color constants: np's _w is float32; inverse from the f32-rounded w ----
static constexpr double W00=(double)0.299f,     W01=(double)0.587f,     W02=(double)0.114f;
static constexpr double W10=(double)-0.168736f, W11=(double)-0.331264f, W12=(double)0.5f;
static constexpr double W20=(double)0.5f,       W21=(double)-0.418688f, W22=(double)-0.081312f;
static constexpr double DETW = W00*(W11*W22 - W12*W21) - W01*(W10*W22 - W12*W20)
                             + W02*(W10*W21 - W11*W20);
static constexpr double I00=(W11*W22-W12*W21)/DETW, I01=(W02*W21-W01*W22)/DETW, I02=(W01*W12-W02*W11)/DETW;
static constexpr double I10=(W12*W20-W10*W22)/DETW, I11=(W00*W22-W02*W20)/DETW, I12=(W02*W10-W00*W12)/DETW;
static constexpr double I20=(W10*W21-W11*W20)/DETW, I21=(W01*W20-W00*W21)/DETW, I22=(W00*W11-W01*W10)/DETW;
static constexpr float  m0f = 125.3f/255.0f, m1f = 123.0f/255.0f, m2f = 113.9f/255.0f;
static constexpr float  s0f = 63.0f/255.0f,  s1f = 62.1f/255.0f,  s2f = 66.7f/255.0f;
static constexpr double M0d = 255.0*(double)m0f, M1d = 255.0*(double)m1f, M2d = 255.0*(double)m2f;
static constexpr double iS0d = 1.0/(255.0*(double)s0f), iS1d = 1.0/(255.0*(double)s1f), iS2d = 1.0/(255.0*(double)s2f);

__global__ void __launch_bounds__(192, 4)
jpeg_kernel(const float* __restrict__ in, float* __restrict__ out) {
#pragma clang fp contract(off)   // pre-round path must not fuse mul+add
  __shared__ _Float16 buf[3 * NBLK * SLOTH];   // 13824 B: V then rec, in place
  __shared__ float Alds[64];
  __shared__ float Qlds[128];

  const int tid  = threadIdx.x;
  const int gid  = blockIdx.x;        // 0..2047
  const int brow = gid >> 3;          // block-row 0..255
  const int qcol = gid & 7;           // quarter-strip 0..7
  const int rowbase = brow * 8;
  const int colbase = qcol * 256;
  const int c   = tid >> 6;           // channel 0..2 (wave-uniform)
  const int sub = tid & 63;
  const int blk = sub & 31;           // spatial block within quarter strip
  const int h   = sub >> 5;           // i-half: rows [0,4) vs [4,8)
  const int i0  = h * 4;

  if (tid < 64)        Alds[tid] = g_AF[tid];
  else if (tid < 192)  Qlds[tid - 64] = g_Q[tid - 64];
  __syncthreads();

  const float* pR = in;
  const float* pG = in + HWP;
  const float* pB = in + 2 * HWP;
  const size_t base = (size_t)rowbase * WW + colbase + blk * 8;

  // per-wave forward color row (f32, as np's _w)
  float wc0, wc1, wc2, bc;
  if (c == 0)      { wc0 = 0.299f;     wc1 = 0.587f;     wc2 = 0.114f;     bc = 0.0f;   }
  else if (c == 1) { wc0 = -0.168736f; wc1 = -0.331264f; wc2 = 0.5f;       bc = 128.0f; }
  else             { wc0 = 0.5f;       wc1 = -0.418688f; wc2 = -0.081312f; bc = 128.0f; }

  // ---- Phase A: RGB -> YUV channel c, f32, BIT-IDENTICAL to the passing R3/R4
  // kernel. Twin half-threads (lane b / b+32) read the same addresses -> L1 hit.
  float X[64];
  #pragma unroll
  for (int r = 0; r < 8; ++r) {
    const float* rowR = pR + base + (size_t)r * WW;
    const float* rowG = pG + base + (size_t)r * WW;
    const float* rowB = pB + base + (size_t)r * WW;
    float4 R0 = *(const float4*)rowR, R1 = *(const float4*)(rowR + 4);
    float4 G0 = *(const float4*)rowG, G1 = *(const float4*)(rowG + 4);
    float4 B0 = *(const float4*)rowB, B1 = *(const float4*)(rowB + 4);
    float fr[8] = {R0.x,R0.y,R0.z,R0.w,R1.x,R1.y,R1.z,R1.w};
    float fg[8] = {G0.x,G0.y,G0.z,G0.w,G1.x,G1.y,G1.z,G1.w};
    float fb[8] = {B0.x,B0.y,B0.z,B0.w,B1.x,B1.y,B1.z,B1.w};
    #pragma unroll
    for (int p = 0; p < 8; ++p) {
      float acc = fmaf(wc2, fb[p], fmaf(wc1, fg[p], wc0 * fr[p]));
      X[r*8+p] = acc + bc;
    }
  }
  const f2* X2 = (const f2*)X;

  // ---- Phase B: rows i0..i0+3 of the np-einsum-order SOP DCT, packed across
  // l-pairs (per-scalar-lane op order identical to R3/R4 -> bit-exact), then
  // quant + fused row-pass IDCT; V row -> LDS as f16.
  _Float16* slot = buf + (c * NBLK + blk) * SLOTH;
  const int qoff = (c == 0) ? 0 : 64;

  for (int ii = 0; ii < 4; ++ii) {              // runtime loop (icache)
    const int i = i0 + ii;
    f2 accs2[4] = {(f2)0.f, (f2)0.f, (f2)0.f, (f2)0.f};
    #pragma unroll
    for (int j = 0; j < 8; ++j) {
      const float aij = Alds[i*8 + j];          // 2-way LDS broadcast (free)
      const f2 av = (f2)aij;
      f2 P2[4];
      #pragma unroll
      for (int kp = 0; kp < 4; ++kp) P2[kp] = av * X2[j*4 + kp];  // fl(aij*Xjk)
      const float* Pp = (const float*)P2;
      #pragma unroll
      for (int lp = 0; lp < 4; ++lp) {
        #pragma unroll
        for (int k = 0; k < 8; ++k) {
          const f2 ap = {AFc[2*lp][k], AFc[2*lp+1][k]};
          f2 t = (f2)Pp[k] * ap;                // fl(P[k]*A[l][k]) per lane
          accs2[lp] = accs2[lp] + t;            // sequential add, k asc, j outer
        }
      }
    }
    // quant epilogue (bit-identical to R3/R4) + fused f32 row-pass IDCT
    const float* ac = (const float*)accs2;
    float Urow[8];
    #pragma unroll
    for (int l = 0; l < 8; ++l) {
      const float q  = Qlds[qoff + i*8 + l];
      const float v  = ac[l] / q;               // IEEE f32 divide
      const float rr = rintf(v);                // half-to-even == np.round
      const float e  = v - rr;
      Urow[l] = (rr + (e * e) * e) * q;
    }
    // V[i][n] = sum_k Urow[k] * A[k][n]  (post-round: packed fma fine)
    f2 vr[4] = {(f2)0.f, (f2)0.f, (f2)0.f, (f2)0.f};
    #pragma unroll
    for (int k = 0; k < 8; ++k) {
      const f2 uk = (f2)Urow[k];
      #pragma unroll
      for (int np = 0; np < 4; ++np) {
        const f2 ar = {AFc[k][2*np], AFc[k][2*np+1]};
        vr[np] = __builtin_elementwise_fma(uk, ar, vr[np]);
      }
    }
    h8 vh;
    const float* vf = (const float*)vr;
    #pragma unroll
    for (int n = 0; n < 8; ++n) vh[n] = (_Float16)vf[n];
    *(h8*)(slot + i*8) = vh;                    // conflict-free b128
  }

  // ---- Col pass: rec[m][n] = sum_j A[j][m] * V[j][n], m in own half.
  // V rows 0-7 of (c,blk) were written by lanes blk / blk+32 of THIS wave ->
  // program order within the wave suffices; no barrier. Read all 8 rows into
  // registers BEFORE overwriting them with rec rows (in-place).
  h8 Vr[8];
  #pragma unroll
  for (int j = 0; j < 8; ++j) Vr[j] = *(const h8*)(slot + j*8);
  float Vf[64];
  #pragma unroll
  for (int j = 0; j < 8; ++j)
    #pragma unroll
    for (int n = 0; n < 8; ++n) Vf[j*8+n] = (float)Vr[j][n];
  const f2* Vf2 = (const f2*)Vf;

  h8 rech[4];
  #pragma unroll
  for (int mm = 0; mm < 4; ++mm) {
    const int m = i0 + mm;
    f2 acc[4] = {(f2)0.f, (f2)0.f, (f2)0.f, (f2)0.f};
    #pragma unroll
    for (int j = 0; j < 8; ++j) {
      const f2 ajm = (f2)Alds[j*8 + m];         // 2-way LDS broadcast
      #pragma unroll
      for (int np = 0; np < 4; ++np)
        acc[np] = __builtin_elementwise_fma(ajm, Vf2[j*4 + np], acc[np]);
    }
    const float* rf = (const float*)acc;
    #pragma unroll
    for (int n = 0; n < 8; ++n) rech[mm][n] = (_Float16)rf[n];
  }
  #pragma unroll
  for (int mm = 0; mm < 4; ++mm)
    *(h8*)(slot + (i0 + mm)*8) = rech[mm];      // overwrite V with rec

  __syncthreads();   // the one cross-channel barrier

  // ---- Phase D: YUV->RGB->normalize; 256 (blk,row) groups over 192 threads
  const float i00=F(I00), i01=F(I01), i02=F(I02);
  const float i10=F(I10), i11=F(I11), i12=F(I12);
  const float i20=F(I20), i21=F(I21), i22=F(I22);
  const float M0=F(M0d), M1=F(M1d), M2=F(M2d);
  const float iS0=F(iS0d), iS1=F(iS1d), iS2=F(iS2d);
  for (int g = tid; g < 256; g += 192) {
    const int b = g & 31;
    const int r = g >> 5;
    const h8 Yv = *(const h8*)(buf + (0*NBLK + b)*SLOTH + r*8);
    const h8 Uv = *(const h8*)(buf + (1*NBLK + b)*SLOTH + r*8);
    const h8 Vv = *(const h8*)(buf + (2*NBLK + b)*SLOTH + r*8);
    float o0[8], o1[8], o2[8];
    #pragma unroll
    for (int p = 0; p < 8; ++p) {
      const float yy = (float)Yv[p];
      const float uu = (float)Uv[p] - 128.0f;
      const float vv = (float)Vv[p] - 128.0f;
      o0[p] = (fmaf(i02, vv, fmaf(i01, uu, i00*yy)) - M0) * iS0;
      o1[p] = (fmaf(i12, vv, fmaf(i11, uu, i10*yy)) - M1) * iS1;
      o2[p] = (fmaf(i22, vv, fmaf(i21, uu, i20*yy)) - M2) * iS2;
    }
    const size_t off = (size_t)(rowbase + r) * WW + colbase + b * 8;
    *(float4*)(out + off)             = make_float4(o0[0],o0[1],o0[2],o0[3]);
    *(float4*)(out + off + 4)         = make_float4(o0[4],o0[5],o0[6],o0[7]);
    *(float4*)(out + HWP + off)       = make_float4(o1[0],o1[1],o1[2],o1[3]);
    *(float4*)(out + HWP + off + 4)   = make_float4(o1[4],o1[5],o1[6],o1[7]);
    *(float4*)(out + 2*HWP + off)     = make_float4(o2[0],o2[1],o2[2],o2[3]);
    *(float4*)(out + 2*HWP + off + 4) = make_float4(o2[4],o2[5],o2[6],o2[7]);
  }
}

extern "C" void kernel_launch(void* const* d_in, const int* in_sizes, int n_in,
                              void* d_out, int out_size, void* d_ws, size_t ws_size,
                              hipStream_t stream) {
  const float* in = (const float*)d_in[0];
  float* out = (float*)d_out;
  dim3 grid((HH/8) * (WW/256));   // 2048 workgroups = 8 per CU
  dim3 block(192);                // 3 waves; wave = 1 channel x 32 blocks x 2 halves
  jpeg_kernel<<<grid, block, 0, stream>>>(in, out);
}